// Round 14
// baseline (4669.326 us; speedup 1.0000x reference)
//
#include <hip/hip_runtime.h>
#include <hip/hip_bf16.h>

typedef __hip_bfloat16 hbf16;
typedef __attribute__((ext_vector_type(8))) short bfrag8;
typedef __attribute__((ext_vector_type(4))) short short4v;
typedef __attribute__((ext_vector_type(4))) float f32x4;
typedef unsigned int u32;

#define BATCH 16
#define HH 512
#define WW 512
#define HWSZ (HH * WW)

// pair-fusion tile: 28x12 output, in-tile 32 granules x 16 rows
// (row = 1024 B = one wave-wide global_load_lds), mid 30x14.
#define PTX 28
#define PTY 12
#define IRW 16
#define ICL 32
#define MRW 14
#define MCL 30
#define MST 30
#define NBX 19   // ceil(512/28)
#define NBY 43   // ceil(512/12)

__device__ __forceinline__ short f2bf(float f) {
    hbf16 h = __float2bfloat16(f);
    return *(short*)&h;
}

__device__ __forceinline__ void gload_lds16(const void* g, void* l) {
    __builtin_amdgcn_global_load_lds(
        (const __attribute__((address_space(1))) u32*)g,
        (__attribute__((address_space(3))) u32*)l, 16, 0, 0);
}

__device__ __forceinline__ float blockSum(float v) {
#pragma unroll
    for (int o = 32; o > 0; o >>= 1) v += __shfl_down(v, o, 64);
    __shared__ float sh[4];
    const int lane = threadIdx.x & 63, wid = threadIdx.x >> 6;
    if (lane == 0) sh[wid] = v;
    __syncthreads();
    float r = 0.f;
    if (threadIdx.x == 0) r = sh[0] + sh[1] + sh[2] + sh[3];
    __syncthreads();
    return r;
}

// ---------------------------------------------------------------------------
// Layer 0 via MFMA: K=18 (k=tap*2+ci) fits one 16x16x32 k-step.
// Tile 64x8, grid (8,64,zc). Writes act NHWC bf16.
// ---------------------------------------------------------------------------
__global__ __launch_bounds__(256) void k_conv_first_mfma(
    const float* __restrict__ p0, long long s0,
    const float* __restrict__ p1, long long s1,
    short* __restrict__ out,
    const float* __restrict__ w0, const float* __restrict__ b0)
{
    __shared__ short sIn[2 * 10 * 67];
    const int tid = threadIdx.x, lane = tid & 63, wvd = tid >> 6;
    const int tx0 = blockIdx.x * 64, ty0 = blockIdx.y * 8;
    const long long b = blockIdx.z;

    const float* pa = p0 + b * s0;
    const float* pb = p1 + b * s1;
    for (int idx = tid; idx < 2 * 10 * 66; idx += 256) {
        const int ci = idx / 660, rem = idx - ci * 660;
        const int yy = rem / 66, xx = rem - yy * 66;
        const int gy = ty0 - 1 + yy, gx = tx0 - 1 + xx;
        float v = 0.f;
        if ((unsigned)gy < (unsigned)HH && (unsigned)gx < (unsigned)WW)
            v = (ci ? pb : pa)[gy * WW + gx];
        sIn[(ci * 10 + yy) * 67 + xx] = f2bf(v);
    }

    const int arow = lane & 15, grp = lane >> 4, lx = lane & 15;
    bfrag8 a0f;
#pragma unroll
    for (int j = 0; j < 8; ++j) {
        const int k = grp * 8 + j;
        a0f[j] = (k < 18) ? f2bf(w0[arow * 18 + (k & 1) * 9 + (k >> 1)])
                          : (short)0;
    }
    const int c0 = grp * 4;
    const float bi0 = b0[c0], bi1 = b0[c0 + 1], bi2 = b0[c0 + 2], bi3 = b0[c0 + 3];
    __syncthreads();

    const int pxl = wvd * 16 + lx;
    for (int y = 0; y < 8; ++y) {
        bfrag8 bf;
#pragma unroll
        for (int j = 0; j < 8; ++j) {
            const int k = grp * 8 + j;
            short v = 0;
            if (k < 18) {
                const int tap = k >> 1, dy = tap / 3, dx = tap - dy * 3;
                v = sIn[((k & 1) * 10 + y + dy) * 67 + (pxl + dx)];
            }
            bf[j] = v;
        }
        f32x4 ac = { bi0, bi1, bi2, bi3 };
        ac = __builtin_amdgcn_mfma_f32_16x16x32_bf16(a0f, bf, ac, 0, 0, 0);
        short4v st;
#pragma unroll
        for (int i = 0; i < 4; ++i) {
            float r = ac[i];
            st[i] = f2bf(r >= 0.f ? r : 0.01f * r);
        }
        *(short4v*)&out[((b * HWSZ + (long long)(ty0 + y) * WW + tx0 + pxl) * 16 + c0)] = st;
    }
}

// ---------------------------------------------------------------------------
// TWO fused conv16 layers with async global->LDS staging.
// In-tile rows are 1024 B -> one wave-wide global_load_lds per row
// (interior rows); border rows use masked loads with zero-fill.
// LDS 29.8 KB -> 5 blocks/CU. MFMA mapping = HW-verified R6/R7 kernels.
// ---------------------------------------------------------------------------
__global__ __launch_bounds__(256) void k_conv16_pair(
    const short* __restrict__ in, short* __restrict__ out,
    const float* __restrict__ wa, const float* __restrict__ ba,
    const float* __restrict__ wb, const float* __restrict__ bb)
{
    __shared__ short bufI[IRW * ICL * 16];   // 16,384 B  [y][x][16ch]
    __shared__ short bufM[MRW * MST * 16];   // 13,440 B  [y][x][16ch]
    const int tid = threadIdx.x, lane = tid & 63, wv = tid >> 6;
    const int tx0 = blockIdx.x * PTX, ty0 = blockIdx.y * PTY;
    const long long b = blockIdx.z;

    // ---- staging: 16 rows, 4 per wave ----
    const bool xInt = (tx0 >= 2) && (tx0 + 30 <= WW);
    for (int r = wv; r < IRW; r += 4) {
        const int gy = ty0 - 2 + r;
        short* ldsrow = &bufI[r * ICL * 16];
        if (xInt && (unsigned)gy < (unsigned)HH) {
            const short* grow = in + (b * HWSZ + (long long)gy * WW + tx0 - 2) * 16;
            gload_lds16((const char*)grow + lane * 16, ldsrow);
        } else {
            const int g = lane >> 1, hf = lane & 1;
            const int gx = tx0 - 2 + g;
            bfrag8 v = {0, 0, 0, 0, 0, 0, 0, 0};
            if ((unsigned)gy < (unsigned)HH && (unsigned)gx < (unsigned)WW)
                v = *(const bfrag8*)&in[(b * HWSZ + (long long)gy * WW + gx) * 16 + hf * 8];
            *(bfrag8*)&ldsrow[g * 16 + hf * 8] = v;
        }
    }

    const int arow = lane & 15, grp = lane >> 4, lx = lane & 15;
    const int half = grp & 1, cib = half * 8, kofb = grp >> 1;
    const int c0 = grp * 4;

    bfrag8 afA[5];
#pragma unroll
    for (int s = 0; s < 5; ++s) {
        const int koff = 2 * s + kofb;
#pragma unroll
        for (int j = 0; j < 8; ++j)
            afA[s][j] = (koff < 9) ? f2bf(wa[(arow * 16 + cib + j) * 9 + koff])
                                   : (short)0;
    }
    const float ba0 = ba[c0], ba1 = ba[c0 + 1], ba2 = ba[c0 + 2], ba3 = ba[c0 + 3];
    __syncthreads();   // drains vmcnt(0): all global_load_lds complete

    // ---- Layer A: bufI -> bufM (14 rows x 30 cols, origin -1) ----
    for (int my = wv; my < MRW; my += 4) {
        f32x4 a0 = { ba0, ba1, ba2, ba3 }, a1 = a0;
#pragma unroll
        for (int s = 0; s < 5; ++s) {
            int koff = 2 * s + kofb;
            if (koff > 8) koff = 8;
            const int dy = koff / 3, dx = koff - dy * 3;
            const short* base = &bufI[(my + dy) * ICL * 16];
            const bfrag8 q0 = *(const bfrag8*)&base[(lx + dx) * 16 + cib];
            const int x1 = min(16 + lx, MCL - 1) + dx;
            const bfrag8 q1 = *(const bfrag8*)&base[x1 * 16 + cib];
            a0 = __builtin_amdgcn_mfma_f32_16x16x32_bf16(afA[s], q0, a0, 0, 0, 0);
            a1 = __builtin_amdgcn_mfma_f32_16x16x32_bf16(afA[s], q1, a1, 0, 0, 0);
        }
        const int gy = ty0 - 1 + my;
        const f32x4 ac[2] = { a0, a1 };
#pragma unroll
        for (int c = 0; c < 2; ++c) {
            const int xr = c * 16 + lx;
            if (xr < MCL) {
                const int gx = tx0 - 1 + xr;
                const bool inim = ((unsigned)gy < (unsigned)HH) &&
                                  ((unsigned)gx < (unsigned)WW);
                short4v st;
#pragma unroll
                for (int i = 0; i < 4; ++i) {
                    float r = ac[c][i];
                    r = (r >= 0.f) ? r : 0.01f * r;
                    st[i] = inim ? f2bf(r) : (short)0;
                }
                *(short4v*)&bufM[(my * MST + xr) * 16 + c0] = st;
            }
        }
    }

    bfrag8 afB[5];
#pragma unroll
    for (int s = 0; s < 5; ++s) {
        const int koff = 2 * s + kofb;
#pragma unroll
        for (int j = 0; j < 8; ++j)
            afB[s][j] = (koff < 9) ? f2bf(wb[(arow * 16 + cib + j) * 9 + koff])
                                   : (short)0;
    }
    const float bb0 = bb[c0], bb1 = bb[c0 + 1], bb2 = bb[c0 + 2], bb3 = bb[c0 + 3];
    __syncthreads();

    // ---- Layer B: bufM -> global (12 rows x 28 cols, origin 0) ----
    for (int oy = wv; oy < PTY; oy += 4) {
        f32x4 a0 = { bb0, bb1, bb2, bb3 }, a1 = a0;
#pragma unroll
        for (int s = 0; s < 5; ++s) {
            int koff = 2 * s + kofb;
            if (koff > 8) koff = 8;
            const int dy = koff / 3, dx = koff - dy * 3;
            const short* base = &bufM[(oy + dy) * MST * 16];
            const bfrag8 q0 = *(const bfrag8*)&base[(lx + dx) * 16 + cib];
            const int x1 = min(16 + lx, PTX - 1) + dx;
            const bfrag8 q1 = *(const bfrag8*)&base[x1 * 16 + cib];
            a0 = __builtin_amdgcn_mfma_f32_16x16x32_bf16(afB[s], q0, a0, 0, 0, 0);
            a1 = __builtin_amdgcn_mfma_f32_16x16x32_bf16(afB[s], q1, a1, 0, 0, 0);
        }
        const int gy = ty0 + oy;
        const f32x4 ac[2] = { a0, a1 };
#pragma unroll
        for (int c = 0; c < 2; ++c) {
            const int xr = c * 16 + lx;
            const int gx = tx0 + xr;
            if (xr < PTX && gy < HH && gx < WW) {
                short4v st;
#pragma unroll
                for (int i = 0; i < 4; ++i) {
                    float r = ac[c][i];
                    st[i] = f2bf(r >= 0.f ? r : 0.01f * r);
                }
                *(short4v*)&out[((b * HWSZ + (long long)gy * WW + gx) * 16 + c0)] = st;
            }
        }
    }
}

// ---------------------------------------------------------------------------
// Last layer via MFMA (R7 verbatim): act NHWC -> clip+median3+(x - med).
// ---------------------------------------------------------------------------
__global__ __launch_bounds__(256) void k_conv_last_mfma(
    const short* __restrict__ in,
    const float* __restrict__ xsrc, long long xstride,
    float* __restrict__ outp,
    const float* __restrict__ w, const float* __restrict__ bias)
{
    __shared__ short s_tile[2 * 10 * 66 * 8];
    const int tid = threadIdx.x;
    const int lane = tid & 63, wvid = tid >> 6;
    const int bx0 = blockIdx.x * 64, by0 = blockIdx.y * 8;
    const short* inb = in + (long long)blockIdx.z * 16 * HWSZ;

    for (int idx = tid; idx < 10 * 66 * 2; idx += 256) {
        const int half = idx & 1, pix = idx >> 1;
        const int yy = pix / 66, xx = pix - yy * 66;
        const int gy = by0 + yy - 1, gx = bx0 + xx - 1;
        bfrag8 v = {0, 0, 0, 0, 0, 0, 0, 0};
        if ((unsigned)gy < (unsigned)HH && (unsigned)gx < (unsigned)WW)
            v = *(const bfrag8*)(inb + ((long long)gy * WW + gx) * 16 + half * 8);
        *(bfrag8*)&s_tile[((half * 10 + yy) * 66 + xx) * 8] = v;
    }

    const int arow = lane & 15;
    const int grp  = lane >> 4;
    const int half = grp & 1;
    const int cib  = half * 8;
    const int kofb = grp >> 1;
    bfrag8 lf[5];
#pragma unroll
    for (int s = 0; s < 5; ++s) {
        const int koff = 2 * s + kofb;
#pragma unroll
        for (int j = 0; j < 8; ++j)
            lf[s][j] = (arow < 3 && koff < 9)
                         ? f2bf(w[(arow * 16 + cib + j) * 9 + koff]) : (short)0;
    }
    const float bi0 = (grp == 0) ? bias[0] : 0.f;
    const float bi1 = (grp == 0) ? bias[1] : 0.f;
    const float bi2 = (grp == 0) ? bias[2] : 0.f;

    __syncthreads();

    const int pxl = wvid * 16 + (lane & 15);
    const int gx = bx0 + pxl;
    const float* xb = xsrc + (long long)blockIdx.z * xstride;
    float* ob = outp + (long long)blockIdx.z * HWSZ;

    for (int yy = 0; yy < 8; ++yy) {
        f32x4 acc = { bi0, bi1, bi2, 0.f };
#pragma unroll
        for (int s = 0; s < 5; ++s) {
            int koff = 2 * s + kofb;
            if (koff > 8) koff = 8;
            const int dy = koff / 3, dx = koff - dy * 3;
            const bfrag8 bfr = *(const bfrag8*)&s_tile[((half * 10 + yy + dy) * 66 + pxl + dx) * 8];
            acc = __builtin_amdgcn_mfma_f32_16x16x32_bf16(lf[s], bfr, acc, 0, 0, 0);
        }
        if (grp == 0) {
            float y0 = fminf(fmaxf(acc[0], -1.f), 1.f);
            float y1 = fminf(fmaxf(acc[1], -1.f), 1.f);
            float y2 = fminf(fmaxf(acc[2], -1.f), 1.f);
            float med = fmaxf(fminf(y0, fmaxf(y1, y2)), fminf(y1, y2));
            const long long pix = (long long)(by0 + yy) * WW + gx;
            ob[pix] = xb[pix] - med;
        }
    }
}

// ---------------------------------------------------------------------------
// Stats over x: float4 loads, per-wave LDS histograms, SSQ
// ---------------------------------------------------------------------------
__global__ __launch_bounds__(256) void k_stats_x(
    const float* __restrict__ x, unsigned* __restrict__ hist, float* __restrict__ sums)
{
    const int p = blockIdx.y;
    const f32x4* src = (const f32x4*)(x + (long long)p * HWSZ);
    __shared__ unsigned h[4][256];
    for (int i = threadIdx.x; i < 1024; i += 256) ((unsigned*)h)[i] = 0;
    __syncthreads();
    const int wid = threadIdx.x >> 6;

    float ss = 0.f;
    for (int i4 = blockIdx.x * 256 + threadIdx.x; i4 < HWSZ / 4; i4 += gridDim.x * 256) {
        const f32x4 v4 = src[i4];
#pragma unroll
        for (int e = 0; e < 4; ++e) {
            const float v = v4[e];
            ss += v * v;
            if (v >= -1.f && v <= 1.f) {
                int idx = (int)floorf((v + 1.f) * 128.f);
                idx = min(max(idx, 0), 255);
                atomicAdd(&h[wid][idx], 1u);
            }
        }
    }
    __syncthreads();
    const unsigned t = h[0][threadIdx.x] + h[1][threadIdx.x] +
                       h[2][threadIdx.x] + h[3][threadIdx.x];
    if (t) atomicAdd(&hist[p * 256 + threadIdx.x], t);

    float bs = blockSum(ss);
    if (threadIdx.x == 0) atomicAdd(&sums[0], bs);
}

// ---------------------------------------------------------------------------
// Stats over deltas, all 3 planes in one dispatch (z = channel).
// ---------------------------------------------------------------------------
__global__ __launch_bounds__(256) void k_stats_delta(
    const float* __restrict__ planes,
    unsigned* __restrict__ hist, float* __restrict__ sums)
{
    const int b = blockIdx.y, cz = blockIdx.z;
    const float* P = planes + ((long long)cz * BATCH + b) * HWSZ;
    const int row = b * 3 + cz;
    __shared__ unsigned h[4][256];
    for (int i = threadIdx.x; i < 1024; i += 256) ((unsigned*)h)[i] = 0;
    __syncthreads();
    const int wid = threadIdx.x >> 6;

    float ss = 0.f;
    for (int i4 = blockIdx.x * 256 + threadIdx.x; i4 < HWSZ / 4; i4 += gridDim.x * 256) {
        const int i0 = i4 * 4;
        const int y = i0 >> 9, x0 = i0 & (WW - 1);
        const f32x4 cur = ((const f32x4*)P)[i4];
        f32x4 up = { 0.f, 0.f, 0.f, 0.f };
        if (y) up = ((const f32x4*)P)[i4 - (WW / 4)];
        const float left = x0 ? P[i0 - 1] : 0.f;
        const float upl = (x0 && y) ? P[i0 - WW - 1] : 0.f;
#pragma unroll
        for (int e = 0; e < 4; ++e) {
            const float v = cur[e];
            const float n = up[e];
            const float wv = e ? cur[e - 1] : left;
            const float nw = e ? up[e - 1] : upl;
            float pr = n + wv - nw;
            pr = fminf(fmaxf(pr, fminf(n, wv)), fmaxf(n, wv));
            const float d = v - pr;
            ss += d * d;
            if (d >= -1.f && d <= 1.f) {
                int idx = (int)floorf((d + 1.f) * 128.f);
                idx = min(max(idx, 0), 255);
                atomicAdd(&h[wid][idx], 1u);
            }
        }
    }
    __syncthreads();
    const unsigned t = h[0][threadIdx.x] + h[1][threadIdx.x] +
                       h[2][threadIdx.x] + h[3][threadIdx.x];
    if (t) atomicAdd(&hist[row * 256 + threadIdx.x], t);

    float bs = blockSum(ss);
    if (threadIdx.x == 0) atomicAdd(&sums[1], bs);
}

// ---------------------------------------------------------------------------
// Finalize: entropies + the 4 output scalars
// ---------------------------------------------------------------------------
__global__ __launch_bounds__(256) void k_finalize(
    const unsigned* __restrict__ hist0, const unsigned* __restrict__ hist1,
    const float* __restrict__ sums, float* __restrict__ out)
{
    float e0 = 0.f, e1 = 0.f;
    for (int i = threadIdx.x; i < 48 * 256; i += 256) {
        float p0 = (float)hist0[i] * (1.0f / HWSZ);
        if (p0 > 0.f) e0 -= p0 * log2f(p0);
        float p1 = (float)hist1[i] * (1.0f / HWSZ);
        if (p1 > 0.f) e1 -= p1 * log2f(p1);
    }
    float t0 = blockSum(e0);
    float t1 = blockSum(e1);
    if (threadIdx.x == 0) {
        const float N = (float)BATCH * 3.f * (float)HWSZ;
        out[0] = 128.f * sqrtf(sums[1] / N);   // loss1 (deltas)
        out[1] = 128.f * sqrtf(sums[0] / N);   // loss0 (x)
        out[2] = t0 * (1.f / (8.f * 48.f));    // invcr0
        out[3] = t1 * (1.f / (8.f * 48.f));    // invcr1
    }
}

// ---------------------------------------------------------------------------
extern "C" void kernel_launch(void* const* d_in, const int* in_sizes, int n_in,
                              void* d_out, int out_size, void* d_ws, size_t ws_size,
                              hipStream_t stream) {
    const float* x = (const float*)d_in[0];
    const float* w[8];
    const float* bs[8];
    for (int i = 0; i < 8; ++i) {
        w[i]  = (const float*)d_in[1 + 2 * i];
        bs[i] = (const float*)d_in[2 + 2 * i];
    }

    // Fixed region: planes (50.33 MB) + hists + sums; act ping-pong adaptive
    // (ws_size = 256 MiB -> chunk 12).
    char* ws = (char*)d_ws;
    size_t o = 0;
    float* rpl = (float*)(ws + o); o += (size_t)BATCH * HWSZ * 4;
    float* gpl = (float*)(ws + o); o += (size_t)BATCH * HWSZ * 4;
    float* bpl = (float*)(ws + o); o += (size_t)BATCH * HWSZ * 4;
    unsigned* hist0 = (unsigned*)(ws + o); o += 48 * 256 * 4;
    unsigned* hist1 = (unsigned*)(ws + o); o += 48 * 256 * 4;
    float* sums = (float*)(ws + o); o += 256;

    const size_t actElems = (size_t)16 * HWSZ;
    const size_t perBatchBytes = 2 * actElems * 2;
    int chunk = 1;
    if (ws_size > o) {
        size_t c = (ws_size - o) / perBatchBytes;
        chunk = (c < 1) ? 1 : (c > BATCH ? BATCH : (int)c);
    }
    short* actA = (short*)(ws + o);
    short* actB = actA + (size_t)chunk * actElems;

    hipMemsetAsync(hist0, 0, 48 * 256 * 4 * 2 + 256, stream);

    auto predictor = [&](const float* pa, long long sa, const float* pb, long long sb,
                         const float* xs, float* outp) {
        for (int b0 = 0; b0 < BATCH; b0 += chunk) {
            const int zc = (BATCH - b0 < chunk) ? (BATCH - b0) : chunk;
            const dim3 g1(WW / 64, HH / 8, zc);
            const dim3 gp(NBX, NBY, zc);
            k_conv_first_mfma<<<g1, 256, 0, stream>>>(
                pa + (long long)b0 * sa, sa, pb + (long long)b0 * sb, sb,
                actA, w[0], bs[0]);
            k_conv16_pair<<<gp, 256, 0, stream>>>(actA, actB, w[1], bs[1], w[2], bs[2]);
            k_conv16_pair<<<gp, 256, 0, stream>>>(actB, actA, w[3], bs[3], w[4], bs[4]);
            k_conv16_pair<<<gp, 256, 0, stream>>>(actA, actB, w[5], bs[5], w[6], bs[6]);
            k_conv_last_mfma<<<g1, 256, 0, stream>>>(
                actB, xs + (long long)b0 * 3 * HWSZ, 3LL * HWSZ,
                outp + (long long)b0 * HWSZ, w[7], bs[7]);
        }
    };

    // r = x_r - pred(g, b);  g = x_g - pred(r, b);  b = x_b - pred(r, g)
    predictor(x + 1LL * HWSZ, 3LL * HWSZ, x + 2LL * HWSZ, 3LL * HWSZ,
              x + 0LL * HWSZ, rpl);
    predictor(rpl, (long long)HWSZ, x + 2LL * HWSZ, 3LL * HWSZ,
              x + 1LL * HWSZ, gpl);
    predictor(rpl, (long long)HWSZ, gpl, (long long)HWSZ,
              x + 2LL * HWSZ, bpl);

    const dim3 sgrid(64, 48);
    k_stats_x<<<sgrid, 256, 0, stream>>>(x, hist0, sums);
    const dim3 dgrid(64, BATCH, 3);
    k_stats_delta<<<dgrid, 256, 0, stream>>>(rpl, hist1, sums);

    k_finalize<<<1, 256, 0, stream>>>(hist0, hist1, sums, (float*)d_out);
}

// Round 17
// 2050.914 us; speedup vs baseline: 2.2767x; 2.2767x over previous
//
#include <hip/hip_runtime.h>
#include <hip/hip_bf16.h>

typedef __hip_bfloat16 hbf16;
typedef __attribute__((ext_vector_type(8))) short bfrag8;
typedef __attribute__((ext_vector_type(4))) short short4v;
typedef __attribute__((ext_vector_type(4))) float f32x4;

#define BATCH 16
#define HH 512
#define WW 512
#define HWSZ (HH * WW)

__device__ __forceinline__ short f2bf(float f) {
    hbf16 h = __float2bfloat16(f);
    return *(short*)&h;
}

__device__ __forceinline__ float blockSum(float v) {
#pragma unroll
    for (int o = 32; o > 0; o >>= 1) v += __shfl_down(v, o, 64);
    __shared__ float sh[4];
    const int lane = threadIdx.x & 63, wid = threadIdx.x >> 6;
    if (lane == 0) sh[wid] = v;
    __syncthreads();
    float r = 0.f;
    if (threadIdx.x == 0) r = sh[0] + sh[1] + sh[2] + sh[3];
    __syncthreads();
    return r;
}

// ---------------------------------------------------------------------------
// Layer 0 via MFMA: K=18 (k=tap*2+ci) fits one 16x16x32 k-step.
// Tile 64x8, grid (8,64,zc). Writes act NHWC bf16.  (R13 verbatim)
// ---------------------------------------------------------------------------
__global__ __launch_bounds__(256) void k_conv_first_mfma(
    const float* __restrict__ p0, long long s0,
    const float* __restrict__ p1, long long s1,
    short* __restrict__ out,
    const float* __restrict__ w0, const float* __restrict__ b0)
{
    __shared__ short sIn[2 * 10 * 67];
    const int tid = threadIdx.x, lane = tid & 63, wvd = tid >> 6;
    const int tx0 = blockIdx.x * 64, ty0 = blockIdx.y * 8;
    const long long b = blockIdx.z;

    const float* pa = p0 + b * s0;
    const float* pb = p1 + b * s1;
    for (int idx = tid; idx < 2 * 10 * 66; idx += 256) {
        const int ci = idx / 660, rem = idx - ci * 660;
        const int yy = rem / 66, xx = rem - yy * 66;
        const int gy = ty0 - 1 + yy, gx = tx0 - 1 + xx;
        float v = 0.f;
        if ((unsigned)gy < (unsigned)HH && (unsigned)gx < (unsigned)WW)
            v = (ci ? pb : pa)[gy * WW + gx];
        sIn[(ci * 10 + yy) * 67 + xx] = f2bf(v);
    }

    const int arow = lane & 15, grp = lane >> 4, lx = lane & 15;
    bfrag8 a0f;
#pragma unroll
    for (int j = 0; j < 8; ++j) {
        const int k = grp * 8 + j;
        a0f[j] = (k < 18) ? f2bf(w0[arow * 18 + (k & 1) * 9 + (k >> 1)])
                          : (short)0;
    }
    const int c0 = grp * 4;
    const float bi0 = b0[c0], bi1 = b0[c0 + 1], bi2 = b0[c0 + 2], bi3 = b0[c0 + 3];
    __syncthreads();

    const int pxl = wvd * 16 + lx;
    for (int y = 0; y < 8; ++y) {
        bfrag8 bf;
#pragma unroll
        for (int j = 0; j < 8; ++j) {
            const int k = grp * 8 + j;
            short v = 0;
            if (k < 18) {
                const int tap = k >> 1, dy = tap / 3, dx = tap - dy * 3;
                v = sIn[((k & 1) * 10 + y + dy) * 67 + (pxl + dx)];
            }
            bf[j] = v;
        }
        f32x4 ac = { bi0, bi1, bi2, bi3 };
        ac = __builtin_amdgcn_mfma_f32_16x16x32_bf16(a0f, bf, ac, 0, 0, 0);
        short4v st;
#pragma unroll
        for (int i = 0; i < 4; ++i) {
            float r = ac[i];
            st[i] = f2bf(r >= 0.f ? r : 0.01f * r);
        }
        *(short4v*)&out[((b * HWSZ + (long long)(ty0 + y) * WW + tx0 + pxl) * 16 + c0)] = st;
    }
}

// ---------------------------------------------------------------------------
// TWO fused conv16 layers, ROLLING-WINDOW: block = 64-wide x 64-row strip.
// Circular 16-row LDS buffers (in: 68 granules/row, mid: 66). Per 8-row step:
// stage 8 in-rows -> bar -> 8 mid rows (layer A) -> bar -> 8 out rows
// (layer B, global write). Slot = row & 15 (consistent for negative rows).
// Race-free: every slot overwrite is barrier-separated from its last reader.
// MFMA mapping = HW-verified R6/R7 kernels. LDS 68.6 KB -> 2 blocks/CU.
// ---------------------------------------------------------------------------
__global__ __launch_bounds__(256) void k_conv16_pair(
    const short* __restrict__ in, short* __restrict__ out,
    const float* __restrict__ wa, const float* __restrict__ ba,
    const float* __restrict__ wb, const float* __restrict__ bb)
{
    __shared__ short bufI[16 * 68 * 16];   // 34,816 B
    __shared__ short bufM[16 * 66 * 16];   // 33,792 B
    const int tid = threadIdx.x, lane = tid & 63, wv = tid >> 6;
    const int tx0 = blockIdx.x * 64;
    const int Y0 = blockIdx.y * 64;
    const short* inb = in + (long long)blockIdx.z * HWSZ * 16;
    short* outb = out + (long long)blockIdx.z * HWSZ * 16;

    const int arow = lane & 15, grp = lane >> 4, lx = lane & 15;
    const int half = grp & 1, cib = half * 8, kofb = grp >> 1;
    const int c0 = grp * 4;

    // A-fragments for both layers + per-s tap offsets
    bfrag8 afA[5], afB[5];
    int dys[5], dxs[5];
#pragma unroll
    for (int s = 0; s < 5; ++s) {
        const int koff = 2 * s + kofb;
        const int kc = (koff < 9) ? koff : 8;
        dys[s] = kc / 3; dxs[s] = kc - dys[s] * 3;
#pragma unroll
        for (int j = 0; j < 8; ++j) {
            afA[s][j] = (koff < 9) ? f2bf(wa[(arow * 16 + cib + j) * 9 + koff]) : (short)0;
            afB[s][j] = (koff < 9) ? f2bf(wb[(arow * 16 + cib + j) * 9 + koff]) : (short)0;
        }
    }
    const float ba0 = ba[c0], ba1 = ba[c0 + 1], ba2 = ba[c0 + 2], ba3 = ba[c0 + 3];
    const float bb0 = bb[c0], bb1 = bb[c0 + 1], bb2 = bb[c0 + 2], bb3 = bb[c0 + 3];

    // stage nrows input rows starting at gbase into circular bufI
    auto STAGE = [&](int gbase, int nrows) {
        const int tot = nrows * 136;               // 68 granules x 2 halves
        for (int i = tid; i < tot; i += 256) {
            const int ro = i / 136, rem = i - ro * 136;
            const int ix = rem >> 1, hf = rem & 1;
            const int gir = gbase + ro, gx = tx0 - 2 + ix;
            bfrag8 v = {0, 0, 0, 0, 0, 0, 0, 0};
            if ((unsigned)gir < (unsigned)HH && (unsigned)gx < (unsigned)WW)
                v = *(const bfrag8*)&inb[((long long)gir * WW + gx) * 16 + hf * 8];
            *(bfrag8*)&bufI[(((gir & 15) * 68) + ix) * 16 + hf * 8] = v;
        }
    };

    // layer A: one mid row (global row gr), cols 0..65 (global tx0-1+col)
    auto MIDROW = [&](int gr) {
        int rofs[5];
#pragma unroll
        for (int s = 0; s < 5; ++s) rofs[s] = ((gr + dys[s] - 1) & 15) * 68;
        const bool rowok = ((unsigned)gr < (unsigned)HH);
        const int mrow = (gr & 15) * 66;
#pragma unroll
        for (int c = 0; c < 5; ++c) {
            const int m = (c < 4) ? (c * 16 + lx) : min(64 + lx, 65);
            f32x4 a = { ba0, ba1, ba2, ba3 };
#pragma unroll
            for (int s = 0; s < 5; ++s) {
                const bfrag8 q = *(const bfrag8*)&bufI[(rofs[s] + m + dxs[s]) * 16 + cib];
                a = __builtin_amdgcn_mfma_f32_16x16x32_bf16(afA[s], q, a, 0, 0, 0);
            }
            const int xr = c * 16 + lx;
            if (xr < 66) {
                const int gx = tx0 - 1 + xr;
                const bool ok = rowok && ((unsigned)gx < (unsigned)WW);
                short4v st;
#pragma unroll
                for (int i = 0; i < 4; ++i) {
                    float r = a[i];
                    r = (r >= 0.f) ? r : 0.01f * r;
                    st[i] = ok ? f2bf(r) : (short)0;
                }
                *(short4v*)&bufM[(mrow + xr) * 16 + c0] = st;
            }
        }
    };

    // layer B: one out row (global row gro), cols 0..63 (global tx0+col)
    auto OUTROW = [&](int gro) {
        int rofs[5];
#pragma unroll
        for (int s = 0; s < 5; ++s) rofs[s] = ((gro + dys[s] - 1) & 15) * 66;
#pragma unroll
        for (int c = 0; c < 4; ++c) {
            const int o = c * 16 + lx;
            f32x4 a = { bb0, bb1, bb2, bb3 };
#pragma unroll
            for (int s = 0; s < 5; ++s) {
                const bfrag8 q = *(const bfrag8*)&bufM[(rofs[s] + o + dxs[s]) * 16 + cib];
                a = __builtin_amdgcn_mfma_f32_16x16x32_bf16(afB[s], q, a, 0, 0, 0);
            }
            short4v st;
#pragma unroll
            for (int i = 0; i < 4; ++i) {
                float r = a[i];
                st[i] = f2bf(r >= 0.f ? r : 0.01f * r);
            }
            *(short4v*)&outb[((long long)gro * WW + tx0 + o) * 16 + c0] = st;
        }
    };

    // prologue: in rows [Y0-2 .. Y0+9], mid rows [Y0-1 .. Y0+8], out band 0
    STAGE(Y0 - 2, 12);
    __syncthreads();
    for (int r = wv; r < 10; r += 4) MIDROW(Y0 - 1 + r);
    __syncthreads();
    for (int r = wv; r < 8; r += 4) OUTROW(Y0 + r);

    // steps 1..7
    for (int k = 1; k < 8; ++k) {
        STAGE(Y0 + 8 * k + 2, 8);
        __syncthreads();
        for (int r = wv; r < 8; r += 4) MIDROW(Y0 + 8 * k + 1 + r);
        __syncthreads();
        for (int r = wv; r < 8; r += 4) OUTROW(Y0 + 8 * k + r);
    }
}

// ---------------------------------------------------------------------------
// Last layer via MFMA (R7 verbatim): act NHWC -> clip+median3+(x - med).
// ---------------------------------------------------------------------------
__global__ __launch_bounds__(256) void k_conv_last_mfma(
    const short* __restrict__ in,
    const float* __restrict__ xsrc, long long xstride,
    float* __restrict__ outp,
    const float* __restrict__ w, const float* __restrict__ bias)
{
    __shared__ short s_tile[2 * 10 * 66 * 8];
    const int tid = threadIdx.x;
    const int lane = tid & 63, wvid = tid >> 6;
    const int bx0 = blockIdx.x * 64, by0 = blockIdx.y * 8;
    const short* inb = in + (long long)blockIdx.z * 16 * HWSZ;

    for (int idx = tid; idx < 10 * 66 * 2; idx += 256) {
        const int half = idx & 1, pix = idx >> 1;
        const int yy = pix / 66, xx = pix - yy * 66;
        const int gy = by0 + yy - 1, gx = bx0 + xx - 1;
        bfrag8 v = {0, 0, 0, 0, 0, 0, 0, 0};
        if ((unsigned)gy < (unsigned)HH && (unsigned)gx < (unsigned)WW)
            v = *(const bfrag8*)(inb + ((long long)gy * WW + gx) * 16 + half * 8);
        *(bfrag8*)&s_tile[((half * 10 + yy) * 66 + xx) * 8] = v;
    }

    const int arow = lane & 15;
    const int grp  = lane >> 4;
    const int half = grp & 1;
    const int cib  = half * 8;
    const int kofb = grp >> 1;
    bfrag8 lf[5];
#pragma unroll
    for (int s = 0; s < 5; ++s) {
        const int koff = 2 * s + kofb;
#pragma unroll
        for (int j = 0; j < 8; ++j)
            lf[s][j] = (arow < 3 && koff < 9)
                         ? f2bf(w[(arow * 16 + cib + j) * 9 + koff]) : (short)0;
    }
    const float bi0 = (grp == 0) ? bias[0] : 0.f;
    const float bi1 = (grp == 0) ? bias[1] : 0.f;
    const float bi2 = (grp == 0) ? bias[2] : 0.f;

    __syncthreads();

    const int pxl = wvid * 16 + (lane & 15);
    const int gx = bx0 + pxl;
    const float* xb = xsrc + (long long)blockIdx.z * xstride;
    float* ob = outp + (long long)blockIdx.z * HWSZ;

    for (int yy = 0; yy < 8; ++yy) {
        f32x4 acc = { bi0, bi1, bi2, 0.f };
#pragma unroll
        for (int s = 0; s < 5; ++s) {
            int koff = 2 * s + kofb;
            if (koff > 8) koff = 8;
            const int dy = koff / 3, dx = koff - dy * 3;
            const bfrag8 bfr = *(const bfrag8*)&s_tile[((half * 10 + yy + dy) * 66 + pxl + dx) * 8];
            acc = __builtin_amdgcn_mfma_f32_16x16x32_bf16(lf[s], bfr, acc, 0, 0, 0);
        }
        if (grp == 0) {
            float y0 = fminf(fmaxf(acc[0], -1.f), 1.f);
            float y1 = fminf(fmaxf(acc[1], -1.f), 1.f);
            float y2 = fminf(fmaxf(acc[2], -1.f), 1.f);
            float med = fmaxf(fminf(y0, fmaxf(y1, y2)), fminf(y1, y2));
            const long long pix = (long long)(by0 + yy) * WW + gx;
            ob[pix] = xb[pix] - med;
        }
    }
}

// ---------------------------------------------------------------------------
// Stats over x: float4 loads, per-wave LDS histograms, SSQ
// ---------------------------------------------------------------------------
__global__ __launch_bounds__(256) void k_stats_x(
    const float* __restrict__ x, unsigned* __restrict__ hist, float* __restrict__ sums)
{
    const int p = blockIdx.y;
    const f32x4* src = (const f32x4*)(x + (long long)p * HWSZ);
    __shared__ unsigned h[4][256];
    for (int i = threadIdx.x; i < 1024; i += 256) ((unsigned*)h)[i] = 0;
    __syncthreads();
    const int wid = threadIdx.x >> 6;

    float ss = 0.f;
    for (int i4 = blockIdx.x * 256 + threadIdx.x; i4 < HWSZ / 4; i4 += gridDim.x * 256) {
        const f32x4 v4 = src[i4];
#pragma unroll
        for (int e = 0; e < 4; ++e) {
            const float v = v4[e];
            ss += v * v;
            if (v >= -1.f && v <= 1.f) {
                int idx = (int)floorf((v + 1.f) * 128.f);
                idx = min(max(idx, 0), 255);
                atomicAdd(&h[wid][idx], 1u);
            }
        }
    }
    __syncthreads();
    const unsigned t = h[0][threadIdx.x] + h[1][threadIdx.x] +
                       h[2][threadIdx.x] + h[3][threadIdx.x];
    if (t) atomicAdd(&hist[p * 256 + threadIdx.x], t);

    float bs = blockSum(ss);
    if (threadIdx.x == 0) atomicAdd(&sums[0], bs);
}

// ---------------------------------------------------------------------------
// Stats over deltas, all 3 planes in one dispatch (z = channel).
// ---------------------------------------------------------------------------
__global__ __launch_bounds__(256) void k_stats_delta(
    const float* __restrict__ planes,
    unsigned* __restrict__ hist, float* __restrict__ sums)
{
    const int b = blockIdx.y, cz = blockIdx.z;
    const float* P = planes + ((long long)cz * BATCH + b) * HWSZ;
    const int row = b * 3 + cz;
    __shared__ unsigned h[4][256];
    for (int i = threadIdx.x; i < 1024; i += 256) ((unsigned*)h)[i] = 0;
    __syncthreads();
    const int wid = threadIdx.x >> 6;

    float ss = 0.f;
    for (int i4 = blockIdx.x * 256 + threadIdx.x; i4 < HWSZ / 4; i4 += gridDim.x * 256) {
        const int i0 = i4 * 4;
        const int y = i0 >> 9, x0 = i0 & (WW - 1);
        const f32x4 cur = ((const f32x4*)P)[i4];
        f32x4 up = { 0.f, 0.f, 0.f, 0.f };
        if (y) up = ((const f32x4*)P)[i4 - (WW / 4)];
        const float left = x0 ? P[i0 - 1] : 0.f;
        const float upl = (x0 && y) ? P[i0 - WW - 1] : 0.f;
#pragma unroll
        for (int e = 0; e < 4; ++e) {
            const float v = cur[e];
            const float n = up[e];
            const float wv = e ? cur[e - 1] : left;
            const float nw = e ? up[e - 1] : upl;
            float pr = n + wv - nw;
            pr = fminf(fmaxf(pr, fminf(n, wv)), fmaxf(n, wv));
            const float d = v - pr;
            ss += d * d;
            if (d >= -1.f && d <= 1.f) {
                int idx = (int)floorf((d + 1.f) * 128.f);
                idx = min(max(idx, 0), 255);
                atomicAdd(&h[wid][idx], 1u);
            }
        }
    }
    __syncthreads();
    const unsigned t = h[0][threadIdx.x] + h[1][threadIdx.x] +
                       h[2][threadIdx.x] + h[3][threadIdx.x];
    if (t) atomicAdd(&hist[row * 256 + threadIdx.x], t);

    float bs = blockSum(ss);
    if (threadIdx.x == 0) atomicAdd(&sums[1], bs);
}

// ---------------------------------------------------------------------------
// Finalize: entropies + the 4 output scalars
// ---------------------------------------------------------------------------
__global__ __launch_bounds__(256) void k_finalize(
    const unsigned* __restrict__ hist0, const unsigned* __restrict__ hist1,
    const float* __restrict__ sums, float* __restrict__ out)
{
    float e0 = 0.f, e1 = 0.f;
    for (int i = threadIdx.x; i < 48 * 256; i += 256) {
        float p0 = (float)hist0[i] * (1.0f / HWSZ);
        if (p0 > 0.f) e0 -= p0 * log2f(p0);
        float p1 = (float)hist1[i] * (1.0f / HWSZ);
        if (p1 > 0.f) e1 -= p1 * log2f(p1);
    }
    float t0 = blockSum(e0);
    float t1 = blockSum(e1);
    if (threadIdx.x == 0) {
        const float N = (float)BATCH * 3.f * (float)HWSZ;
        out[0] = 128.f * sqrtf(sums[1] / N);   // loss1 (deltas)
        out[1] = 128.f * sqrtf(sums[0] / N);   // loss0 (x)
        out[2] = t0 * (1.f / (8.f * 48.f));    // invcr0
        out[3] = t1 * (1.f / (8.f * 48.f));    // invcr1
    }
}

// ---------------------------------------------------------------------------
extern "C" void kernel_launch(void* const* d_in, const int* in_sizes, int n_in,
                              void* d_out, int out_size, void* d_ws, size_t ws_size,
                              hipStream_t stream) {
    const float* x = (const float*)d_in[0];
    const float* w[8];
    const float* bs[8];
    for (int i = 0; i < 8; ++i) {
        w[i]  = (const float*)d_in[1 + 2 * i];
        bs[i] = (const float*)d_in[2 + 2 * i];
    }

    // Fixed region: planes (50.33 MB) + hists + sums; act ping-pong adaptive
    // (ws_size = 256 MiB -> chunk 12).
    char* ws = (char*)d_ws;
    size_t o = 0;
    float* rpl = (float*)(ws + o); o += (size_t)BATCH * HWSZ * 4;
    float* gpl = (float*)(ws + o); o += (size_t)BATCH * HWSZ * 4;
    float* bpl = (float*)(ws + o); o += (size_t)BATCH * HWSZ * 4;
    unsigned* hist0 = (unsigned*)(ws + o); o += 48 * 256 * 4;
    unsigned* hist1 = (unsigned*)(ws + o); o += 48 * 256 * 4;
    float* sums = (float*)(ws + o); o += 256;

    const size_t actElems = (size_t)16 * HWSZ;
    const size_t perBatchBytes = 2 * actElems * 2;
    int chunk = 1;
    if (ws_size > o) {
        size_t c = (ws_size - o) / perBatchBytes;
        chunk = (c < 1) ? 1 : (c > BATCH ? BATCH : (int)c);
    }
    short* actA = (short*)(ws + o);
    short* actB = actA + (size_t)chunk * actElems;

    hipMemsetAsync(hist0, 0, 48 * 256 * 4 * 2 + 256, stream);

    auto predictor = [&](const float* pa, long long sa, const float* pb, long long sb,
                         const float* xs, float* outp) {
        for (int b0 = 0; b0 < BATCH; b0 += chunk) {
            const int zc = (BATCH - b0 < chunk) ? (BATCH - b0) : chunk;
            const dim3 g1(WW / 64, HH / 8, zc);
            const dim3 gp(WW / 64, HH / 64, zc);
            k_conv_first_mfma<<<g1, 256, 0, stream>>>(
                pa + (long long)b0 * sa, sa, pb + (long long)b0 * sb, sb,
                actA, w[0], bs[0]);
            k_conv16_pair<<<gp, 256, 0, stream>>>(actA, actB, w[1], bs[1], w[2], bs[2]);
            k_conv16_pair<<<gp, 256, 0, stream>>>(actB, actA, w[3], bs[3], w[4], bs[4]);
            k_conv16_pair<<<gp, 256, 0, stream>>>(actA, actB, w[5], bs[5], w[6], bs[6]);
            k_conv_last_mfma<<<g1, 256, 0, stream>>>(
                actB, xs + (long long)b0 * 3 * HWSZ, 3LL * HWSZ,
                outp + (long long)b0 * HWSZ, w[7], bs[7]);
        }
    };

    // r = x_r - pred(g, b);  g = x_g - pred(r, b);  b = x_b - pred(r, g)
    predictor(x + 1LL * HWSZ, 3LL * HWSZ, x + 2LL * HWSZ, 3LL * HWSZ,
              x + 0LL * HWSZ, rpl);
    predictor(rpl, (long long)HWSZ, x + 2LL * HWSZ, 3LL * HWSZ,
              x + 1LL * HWSZ, gpl);
    predictor(rpl, (long long)HWSZ, gpl, (long long)HWSZ,
              x + 2LL * HWSZ, bpl);

    const dim3 sgrid(64, 48);
    k_stats_x<<<sgrid, 256, 0, stream>>>(x, hist0, sums);
    const dim3 dgrid(64, BATCH, 3);
    k_stats_delta<<<dgrid, 256, 0, stream>>>(rpl, hist1, sums);

    k_finalize<<<1, 256, 0, stream>>>(hist0, hist1, sums, (float*)d_out);
}

// Round 18
// 1550.216 us; speedup vs baseline: 3.0120x; 1.3230x over previous
//
#include <hip/hip_runtime.h>
#include <hip/hip_bf16.h>

typedef __hip_bfloat16 hbf16;
typedef __attribute__((ext_vector_type(8))) short bfrag8;
typedef __attribute__((ext_vector_type(4))) short short4v;
typedef __attribute__((ext_vector_type(4))) float f32x4;

#define BATCH 16
#define HH 512
#define WW 512
#define HWSZ (HH * WW)
#define STRIPH 64
#define NSTEP (STRIPH / 4)

__device__ __forceinline__ short f2bf(float f) {
    hbf16 h = __float2bfloat16(f);
    return *(short*)&h;
}

__device__ __forceinline__ float blockSum(float v) {
#pragma unroll
    for (int o = 32; o > 0; o >>= 1) v += __shfl_down(v, o, 64);
    __shared__ float sh[4];
    const int lane = threadIdx.x & 63, wid = threadIdx.x >> 6;
    if (lane == 0) sh[wid] = v;
    __syncthreads();
    float r = 0.f;
    if (threadIdx.x == 0) r = sh[0] + sh[1] + sh[2] + sh[3];
    __syncthreads();
    return r;
}

// Generic conv16 row into an LDS window. Names captured from enclosing scope:
// lx, cib, c0, tx0, dys, dxs. AF must be a named bfrag8[5] (stays in regs).
#define CONV_ROW(INW, IW, OUTW, OW, AF, B0_, B1_, B2_, B3_, GR) do {          \
    const int gr_ = (GR);                                                      \
    const bool rok_ = ((unsigned)gr_ < (unsigned)HH);                          \
    const int halo_ = ((OW) - 64) / 2;                                         \
    const int rslot_ = (gr_ & 7) * (OW);                                       \
    _Pragma("unroll")                                                          \
    for (int c_ = 0; c_ < 5; ++c_) {                                           \
        const int xr_ = c_ * 16 + lx;                                          \
        const int xc_ = (xr_ < (OW)) ? xr_ : ((OW) - 1);                       \
        f32x4 a_ = { B0_, B1_, B2_, B3_ };                                     \
        _Pragma("unroll")                                                      \
        for (int s_ = 0; s_ < 5; ++s_) {                                       \
            const bfrag8 q_ = *(const bfrag8*)&(INW)[(((gr_ + dys[s_] - 1) & 7) * (IW) + (xc_ + dxs[s_])) * 16 + cib]; \
            a_ = __builtin_amdgcn_mfma_f32_16x16x32_bf16(AF[s_], q_, a_, 0, 0, 0); \
        }                                                                      \
        if (xr_ < (OW)) {                                                      \
            const int gx_ = tx0 - halo_ + xr_;                                 \
            const bool ok_ = rok_ && ((unsigned)gx_ < (unsigned)WW);           \
            short4v st_;                                                       \
            _Pragma("unroll")                                                  \
            for (int i_ = 0; i_ < 4; ++i_) {                                   \
                float r_ = a_[i_]; r_ = (r_ >= 0.f) ? r_ : 0.01f * r_;         \
                st_[i_] = ok_ ? f2bf(r_) : (short)0;                           \
            }                                                                  \
            *(short4v*)&(OUTW)[(rslot_ + xr_) * 16 + c0] = st_;                \
        }                                                                      \
    }                                                                          \
} while (0)

// ---------------------------------------------------------------------------
// quadA: L0(2ch fp32 -> 16) + L1 + L2 + L3, rolling window over a 64x64 strip.
// Windows (8 rows, circular): fin 72w(2ch), a0 70w, a1 68w, a2 66w. 54.5 KB.
// Per 4-row step: STAGE -> bar -> L0 -> bar -> L1 -> bar -> L2 -> bar -> L3out.
// Slot overwrites barrier-separated from last readers (offsets: +4/+3/+2/+1/0).
// ---------------------------------------------------------------------------
__global__ __launch_bounds__(256) void k_quadA(
    const float* __restrict__ p0, long long s0,
    const float* __restrict__ p1, long long s1,
    short* __restrict__ outA,
    const float* __restrict__ w0, const float* __restrict__ b0,
    const float* __restrict__ w1, const float* __restrict__ b1,
    const float* __restrict__ w2, const float* __restrict__ b2,
    const float* __restrict__ w3, const float* __restrict__ b3)
{
    __shared__ short finW[8 * 72 * 2];     //  2,304 B
    __shared__ short a0W[8 * 70 * 16];     // 17,920 B
    __shared__ short a1W[8 * 68 * 16];     // 17,408 B
    __shared__ short a2W[8 * 66 * 16];     // 16,896 B

    const int tid = threadIdx.x, lane = tid & 63, wv = tid >> 6;
    const int tx0 = blockIdx.x * 64, Y0 = blockIdx.y * STRIPH;
    const long long b = blockIdx.z;
    const float* pa = p0 + b * s0;
    const float* pb = p1 + b * s1;
    short* outb = outA + b * (long long)HWSZ * 16;

    const int arow = lane & 15, grp = lane >> 4, lx = lane & 15;
    const int half = grp & 1, cib = half * 8, kofb = grp >> 1;
    const int c0 = grp * 4;

    bfrag8 a0f;
#pragma unroll
    for (int j = 0; j < 8; ++j) {
        const int k = grp * 8 + j;
        a0f[j] = (k < 18) ? f2bf(w0[arow * 18 + (k & 1) * 9 + (k >> 1)]) : (short)0;
    }
    bfrag8 af1[5], af2[5], af3[5];
    int dys[5], dxs[5];
#pragma unroll
    for (int s = 0; s < 5; ++s) {
        const int koff = 2 * s + kofb;
        const int kc = (koff < 9) ? koff : 8;
        dys[s] = kc / 3; dxs[s] = kc - dys[s] * 3;
#pragma unroll
        for (int j = 0; j < 8; ++j) {
            af1[s][j] = (koff < 9) ? f2bf(w1[(arow * 16 + cib + j) * 9 + koff]) : (short)0;
            af2[s][j] = (koff < 9) ? f2bf(w2[(arow * 16 + cib + j) * 9 + koff]) : (short)0;
            af3[s][j] = (koff < 9) ? f2bf(w3[(arow * 16 + cib + j) * 9 + koff]) : (short)0;
        }
    }
    const float b00 = b0[c0], b01 = b0[c0 + 1], b02 = b0[c0 + 2], b03 = b0[c0 + 3];
    const float b10 = b1[c0], b11 = b1[c0 + 1], b12 = b1[c0 + 2], b13 = b1[c0 + 3];
    const float b20 = b2[c0], b21 = b2[c0 + 1], b22 = b2[c0 + 2], b23 = b2[c0 + 3];
    const float b30 = b3[c0], b31 = b3[c0 + 1], b32 = b3[c0 + 2], b33 = b3[c0 + 3];

    auto STAGE = [&](int r0, int nr) {
        const int tot = nr * 144;   // 72 px x 2 ch
        for (int i = tid; i < tot; i += 256) {
            const int rr = i / 144, rem = i - rr * 144, xx = rem >> 1, ci = rem & 1;
            const int gr = r0 + rr, gx = tx0 - 4 + xx;
            float v = 0.f;
            if ((unsigned)gr < (unsigned)HH && (unsigned)gx < (unsigned)WW)
                v = (ci ? pb : pa)[gr * WW + gx];
            finW[((gr & 7) * 72 + xx) * 2 + ci] = f2bf(v);
        }
    };

    auto L0ROW = [&](int gr) {   // a0 row gr, width 70, out base tx0-3
        const bool rok = ((unsigned)gr < (unsigned)HH);
        const int rslot = (gr & 7) * 70;
#pragma unroll
        for (int c = 0; c < 5; ++c) {
            const int xr = c * 16 + lx;
            const int xc = (xr < 70) ? xr : 69;
            bfrag8 bf;
#pragma unroll
            for (int j = 0; j < 8; ++j) {
                const int k = grp * 8 + j;
                short v = 0;
                if (k < 18) {
                    const int tap = k >> 1, dy = tap / 3, dx = tap - dy * 3;
                    v = finW[(((gr + dy - 1) & 7) * 72 + (xc + dx)) * 2 + (k & 1)];
                }
                bf[j] = v;
            }
            f32x4 a = { b00, b01, b02, b03 };
            a = __builtin_amdgcn_mfma_f32_16x16x32_bf16(a0f, bf, a, 0, 0, 0);
            if (xr < 70) {
                const int gx = tx0 - 3 + xr;
                const bool ok = rok && ((unsigned)gx < (unsigned)WW);
                short4v st;
#pragma unroll
                for (int i = 0; i < 4; ++i) {
                    float r = a[i]; r = (r >= 0.f) ? r : 0.01f * r;
                    st[i] = ok ? f2bf(r) : (short)0;
                }
                *(short4v*)&a0W[(rslot + xr) * 16 + c0] = st;
            }
        }
    };

    auto OUT3 = [&](int gr) {    // rows/cols always in-image
#pragma unroll
        for (int c = 0; c < 4; ++c) {
            const int o = c * 16 + lx;
            f32x4 a = { b30, b31, b32, b33 };
#pragma unroll
            for (int s = 0; s < 5; ++s) {
                const bfrag8 q = *(const bfrag8*)&a2W[(((gr + dys[s] - 1) & 7) * 66 + (o + dxs[s])) * 16 + cib];
                a = __builtin_amdgcn_mfma_f32_16x16x32_bf16(af3[s], q, a, 0, 0, 0);
            }
            short4v st;
#pragma unroll
            for (int i = 0; i < 4; ++i) {
                float r = a[i];
                st[i] = f2bf(r >= 0.f ? r : 0.01f * r);
            }
            *(short4v*)&outb[((long long)gr * WW + tx0 + o) * 16 + c0] = st;
        }
    };

    // prologue
    STAGE(Y0 - 4, 8);
    __syncthreads();
    L0ROW(Y0 - 3 + wv);
    if (wv < 2) L0ROW(Y0 + 1 + wv);
    __syncthreads();
    CONV_ROW(a0W, 70, a1W, 68, af1, b10, b11, b12, b13, Y0 - 2 + wv);
    __syncthreads();
    if (wv < 2) CONV_ROW(a1W, 68, a2W, 66, af2, b20, b21, b22, b23, Y0 - 1 + wv);
    __syncthreads();

    for (int k = 0; k < NSTEP; ++k) {
        const int base = Y0 + 4 * k;
        STAGE(base + 4, 4);
        __syncthreads();
        L0ROW(base + 3 + wv);
        __syncthreads();
        CONV_ROW(a0W, 70, a1W, 68, af1, b10, b11, b12, b13, base + 2 + wv);
        __syncthreads();
        CONV_ROW(a1W, 68, a2W, 66, af2, b20, b21, b22, b23, base + 1 + wv);
        __syncthreads();
        OUT3(base + wv);
    }
}

// ---------------------------------------------------------------------------
// quadB: L4 + L5 + L6 + L7(clip/median3/subtract), same rolling structure.
// Windows: in 72w, a4 70w, a5 68w, a6 66w (all 16ch). 70.7 KB -> 2 blocks/CU.
// ---------------------------------------------------------------------------
__global__ __launch_bounds__(256) void k_quadB(
    const short* __restrict__ inA,
    const float* __restrict__ xsrc, long long xstride,
    float* __restrict__ outp,
    const float* __restrict__ w4, const float* __restrict__ b4,
    const float* __restrict__ w5, const float* __restrict__ b5,
    const float* __restrict__ w6, const float* __restrict__ b6,
    const float* __restrict__ w7, const float* __restrict__ b7)
{
    __shared__ short inW[8 * 72 * 16];    // 18,432 B
    __shared__ short a4W[8 * 70 * 16];    // 17,920 B
    __shared__ short a5W[8 * 68 * 16];    // 17,408 B
    __shared__ short a6W[8 * 66 * 16];    // 16,896 B

    const int tid = threadIdx.x, lane = tid & 63, wv = tid >> 6;
    const int tx0 = blockIdx.x * 64, Y0 = blockIdx.y * STRIPH;
    const long long b = blockIdx.z;
    const short* inb = inA + b * (long long)HWSZ * 16;
    const float* xb = xsrc + b * xstride;
    float* ob = outp + b * (long long)HWSZ;

    const int arow = lane & 15, grp = lane >> 4, lx = lane & 15;
    const int half = grp & 1, cib = half * 8, kofb = grp >> 1;
    const int c0 = grp * 4;

    bfrag8 af4[5], af5[5], af6[5], lf[5];
    int dys[5], dxs[5];
#pragma unroll
    for (int s = 0; s < 5; ++s) {
        const int koff = 2 * s + kofb;
        const int kc = (koff < 9) ? koff : 8;
        dys[s] = kc / 3; dxs[s] = kc - dys[s] * 3;
#pragma unroll
        for (int j = 0; j < 8; ++j) {
            af4[s][j] = (koff < 9) ? f2bf(w4[(arow * 16 + cib + j) * 9 + koff]) : (short)0;
            af5[s][j] = (koff < 9) ? f2bf(w5[(arow * 16 + cib + j) * 9 + koff]) : (short)0;
            af6[s][j] = (koff < 9) ? f2bf(w6[(arow * 16 + cib + j) * 9 + koff]) : (short)0;
            lf[s][j]  = (arow < 3 && koff < 9) ? f2bf(w7[(arow * 16 + cib + j) * 9 + koff]) : (short)0;
        }
    }
    const float b40 = b4[c0], b41 = b4[c0 + 1], b42 = b4[c0 + 2], b43 = b4[c0 + 3];
    const float b50 = b5[c0], b51 = b5[c0 + 1], b52 = b5[c0 + 2], b53 = b5[c0 + 3];
    const float b60 = b6[c0], b61 = b6[c0 + 1], b62 = b6[c0 + 2], b63 = b6[c0 + 3];
    const float lb0 = (grp == 0) ? b7[0] : 0.f;
    const float lb1 = (grp == 0) ? b7[1] : 0.f;
    const float lb2 = (grp == 0) ? b7[2] : 0.f;

    auto STAGEB = [&](int r0, int nr) {
        const int tot = nr * 144;   // 72 granules x 2 halves
        for (int i = tid; i < tot; i += 256) {
            const int rr = i / 144, rem = i - rr * 144, ix = rem >> 1, hf = rem & 1;
            const int gr = r0 + rr, gx = tx0 - 4 + ix;
            bfrag8 v = {0, 0, 0, 0, 0, 0, 0, 0};
            if ((unsigned)gr < (unsigned)HH && (unsigned)gx < (unsigned)WW)
                v = *(const bfrag8*)&inb[((long long)gr * WW + gx) * 16 + hf * 8];
            *(bfrag8*)&inW[((gr & 7) * 72 + ix) * 16 + hf * 8] = v;
        }
    };

    auto OUT7 = [&](int gr) {
#pragma unroll
        for (int c = 0; c < 4; ++c) {
            const int o = c * 16 + lx;
            f32x4 a = { lb0, lb1, lb2, 0.f };
#pragma unroll
            for (int s = 0; s < 5; ++s) {
                const bfrag8 q = *(const bfrag8*)&a6W[(((gr + dys[s] - 1) & 7) * 66 + (o + dxs[s])) * 16 + cib];
                a = __builtin_amdgcn_mfma_f32_16x16x32_bf16(lf[s], q, a, 0, 0, 0);
            }
            if (grp == 0) {
                float y0 = fminf(fmaxf(a[0], -1.f), 1.f);
                float y1 = fminf(fmaxf(a[1], -1.f), 1.f);
                float y2 = fminf(fmaxf(a[2], -1.f), 1.f);
                float med = fmaxf(fminf(y0, fmaxf(y1, y2)), fminf(y1, y2));
                const long long pix = (long long)gr * WW + tx0 + o;
                ob[pix] = xb[pix] - med;
            }
        }
    };

    // prologue
    STAGEB(Y0 - 4, 8);
    __syncthreads();
    CONV_ROW(inW, 72, a4W, 70, af4, b40, b41, b42, b43, Y0 - 3 + wv);
    if (wv < 2) CONV_ROW(inW, 72, a4W, 70, af4, b40, b41, b42, b43, Y0 + 1 + wv);
    __syncthreads();
    CONV_ROW(a4W, 70, a5W, 68, af5, b50, b51, b52, b53, Y0 - 2 + wv);
    __syncthreads();
    if (wv < 2) CONV_ROW(a5W, 68, a6W, 66, af6, b60, b61, b62, b63, Y0 - 1 + wv);
    __syncthreads();

    for (int k = 0; k < NSTEP; ++k) {
        const int base = Y0 + 4 * k;
        STAGEB(base + 4, 4);
        __syncthreads();
        CONV_ROW(inW, 72, a4W, 70, af4, b40, b41, b42, b43, base + 3 + wv);
        __syncthreads();
        CONV_ROW(a4W, 70, a5W, 68, af5, b50, b51, b52, b53, base + 2 + wv);
        __syncthreads();
        CONV_ROW(a5W, 68, a6W, 66, af6, b60, b61, b62, b63, base + 1 + wv);
        __syncthreads();
        OUT7(base + wv);
    }
}

// ---------------------------------------------------------------------------
// Stats over x: float4 loads, per-wave LDS histograms, SSQ
// ---------------------------------------------------------------------------
__global__ __launch_bounds__(256) void k_stats_x(
    const float* __restrict__ x, unsigned* __restrict__ hist, float* __restrict__ sums)
{
    const int p = blockIdx.y;
    const f32x4* src = (const f32x4*)(x + (long long)p * HWSZ);
    __shared__ unsigned h[4][256];
    for (int i = threadIdx.x; i < 1024; i += 256) ((unsigned*)h)[i] = 0;
    __syncthreads();
    const int wid = threadIdx.x >> 6;

    float ss = 0.f;
    for (int i4 = blockIdx.x * 256 + threadIdx.x; i4 < HWSZ / 4; i4 += gridDim.x * 256) {
        const f32x4 v4 = src[i4];
#pragma unroll
        for (int e = 0; e < 4; ++e) {
            const float v = v4[e];
            ss += v * v;
            if (v >= -1.f && v <= 1.f) {
                int idx = (int)floorf((v + 1.f) * 128.f);
                idx = min(max(idx, 0), 255);
                atomicAdd(&h[wid][idx], 1u);
            }
        }
    }
    __syncthreads();
    const unsigned t = h[0][threadIdx.x] + h[1][threadIdx.x] +
                       h[2][threadIdx.x] + h[3][threadIdx.x];
    if (t) atomicAdd(&hist[p * 256 + threadIdx.x], t);

    float bs = blockSum(ss);
    if (threadIdx.x == 0) atomicAdd(&sums[0], bs);
}

// ---------------------------------------------------------------------------
// Stats over deltas, all 3 planes in one dispatch (z = channel).
// ---------------------------------------------------------------------------
__global__ __launch_bounds__(256) void k_stats_delta(
    const float* __restrict__ planes,
    unsigned* __restrict__ hist, float* __restrict__ sums)
{
    const int b = blockIdx.y, cz = blockIdx.z;
    const float* P = planes + ((long long)cz * BATCH + b) * HWSZ;
    const int row = b * 3 + cz;
    __shared__ unsigned h[4][256];
    for (int i = threadIdx.x; i < 1024; i += 256) ((unsigned*)h)[i] = 0;
    __syncthreads();
    const int wid = threadIdx.x >> 6;

    float ss = 0.f;
    for (int i4 = blockIdx.x * 256 + threadIdx.x; i4 < HWSZ / 4; i4 += gridDim.x * 256) {
        const int i0 = i4 * 4;
        const int y = i0 >> 9, x0 = i0 & (WW - 1);
        const f32x4 cur = ((const f32x4*)P)[i4];
        f32x4 up = { 0.f, 0.f, 0.f, 0.f };
        if (y) up = ((const f32x4*)P)[i4 - (WW / 4)];
        const float left = x0 ? P[i0 - 1] : 0.f;
        const float upl = (x0 && y) ? P[i0 - WW - 1] : 0.f;
#pragma unroll
        for (int e = 0; e < 4; ++e) {
            const float v = cur[e];
            const float n = up[e];
            const float wv = e ? cur[e - 1] : left;
            const float nw = e ? up[e - 1] : upl;
            float pr = n + wv - nw;
            pr = fminf(fmaxf(pr, fminf(n, wv)), fmaxf(n, wv));
            const float d = v - pr;
            ss += d * d;
            if (d >= -1.f && d <= 1.f) {
                int idx = (int)floorf((d + 1.f) * 128.f);
                idx = min(max(idx, 0), 255);
                atomicAdd(&h[wid][idx], 1u);
            }
        }
    }
    __syncthreads();
    const unsigned t = h[0][threadIdx.x] + h[1][threadIdx.x] +
                       h[2][threadIdx.x] + h[3][threadIdx.x];
    if (t) atomicAdd(&hist[row * 256 + threadIdx.x], t);

    float bs = blockSum(ss);
    if (threadIdx.x == 0) atomicAdd(&sums[1], bs);
}

// ---------------------------------------------------------------------------
// Finalize: entropies + the 4 output scalars
// ---------------------------------------------------------------------------
__global__ __launch_bounds__(256) void k_finalize(
    const unsigned* __restrict__ hist0, const unsigned* __restrict__ hist1,
    const float* __restrict__ sums, float* __restrict__ out)
{
    float e0 = 0.f, e1 = 0.f;
    for (int i = threadIdx.x; i < 48 * 256; i += 256) {
        float p0 = (float)hist0[i] * (1.0f / HWSZ);
        if (p0 > 0.f) e0 -= p0 * log2f(p0);
        float p1 = (float)hist1[i] * (1.0f / HWSZ);
        if (p1 > 0.f) e1 -= p1 * log2f(p1);
    }
    float t0 = blockSum(e0);
    float t1 = blockSum(e1);
    if (threadIdx.x == 0) {
        const float N = (float)BATCH * 3.f * (float)HWSZ;
        out[0] = 128.f * sqrtf(sums[1] / N);   // loss1 (deltas)
        out[1] = 128.f * sqrtf(sums[0] / N);   // loss0 (x)
        out[2] = t0 * (1.f / (8.f * 48.f));    // invcr0
        out[3] = t1 * (1.f / (8.f * 48.f));    // invcr1
    }
}

// ---------------------------------------------------------------------------
extern "C" void kernel_launch(void* const* d_in, const int* in_sizes, int n_in,
                              void* d_out, int out_size, void* d_ws, size_t ws_size,
                              hipStream_t stream) {
    const float* x = (const float*)d_in[0];
    const float* w[8];
    const float* bs[8];
    for (int i = 0; i < 8; ++i) {
        w[i]  = (const float*)d_in[1 + 2 * i];
        bs[i] = (const float*)d_in[2 + 2 * i];
    }

    // Fixed region: planes (50.33 MB) + hists + sums; ONE act buffer
    // (8.39 MB/batch) sized adaptively -> chunk = 16 at ws_size = 256 MiB.
    char* ws = (char*)d_ws;
    size_t o = 0;
    float* rpl = (float*)(ws + o); o += (size_t)BATCH * HWSZ * 4;
    float* gpl = (float*)(ws + o); o += (size_t)BATCH * HWSZ * 4;
    float* bpl = (float*)(ws + o); o += (size_t)BATCH * HWSZ * 4;
    unsigned* hist0 = (unsigned*)(ws + o); o += 48 * 256 * 4;
    unsigned* hist1 = (unsigned*)(ws + o); o += 48 * 256 * 4;
    float* sums = (float*)(ws + o); o += 256;

    const size_t actElems = (size_t)16 * HWSZ;          // shorts per batch
    const size_t perBatchBytes = actElems * 2;          // single buffer
    int chunk = 1;
    if (ws_size > o) {
        size_t c = (ws_size - o) / perBatchBytes;
        chunk = (c < 1) ? 1 : (c > BATCH ? BATCH : (int)c);
    }
    short* actA = (short*)(ws + o);

    hipMemsetAsync(hist0, 0, 48 * 256 * 4 * 2 + 256, stream);

    auto predictor = [&](const float* pa, long long sa, const float* pb, long long sb,
                         const float* xs, float* outp) {
        for (int b0 = 0; b0 < BATCH; b0 += chunk) {
            const int zc = (BATCH - b0 < chunk) ? (BATCH - b0) : chunk;
            const dim3 gq(WW / 64, HH / STRIPH, zc);
            k_quadA<<<gq, 256, 0, stream>>>(
                pa + (long long)b0 * sa, sa, pb + (long long)b0 * sb, sb,
                actA, w[0], bs[0], w[1], bs[1], w[2], bs[2], w[3], bs[3]);
            k_quadB<<<gq, 256, 0, stream>>>(
                actA, xs + (long long)b0 * 3 * HWSZ, 3LL * HWSZ,
                outp + (long long)b0 * HWSZ,
                w[4], bs[4], w[5], bs[5], w[6], bs[6], w[7], bs[7]);
        }
    };

    // r = x_r - pred(g, b);  g = x_g - pred(r, b);  b = x_b - pred(r, g)
    predictor(x + 1LL * HWSZ, 3LL * HWSZ, x + 2LL * HWSZ, 3LL * HWSZ,
              x + 0LL * HWSZ, rpl);
    predictor(rpl, (long long)HWSZ, x + 2LL * HWSZ, 3LL * HWSZ,
              x + 1LL * HWSZ, gpl);
    predictor(rpl, (long long)HWSZ, gpl, (long long)HWSZ,
              x + 2LL * HWSZ, bpl);

    const dim3 sgrid(64, 48);
    k_stats_x<<<sgrid, 256, 0, stream>>>(x, hist0, sums);
    const dim3 dgrid(64, BATCH, 3);
    k_stats_delta<<<dgrid, 256, 0, stream>>>(rpl, hist1, sums);

    k_finalize<<<1, 256, 0, stream>>>(hist0, hist1, sums, (float*)d_out);
}